// Round 17
// baseline (215.853 us; speedup 1.0000x reference)
//
#include <hip/hip_runtime.h>
#include <math.h>

// Problem constants
constexpr int SEQ   = 512;
constexpr int HDIM  = 64;
constexpr int NHEAD = 12;
constexpr int NBATCH = 2;
constexpr int CDIM  = 768;
constexpr int TOPM  = 16;
constexpr int SMAX  = 8;
constexpr float NEGINF = -1e30f;

typedef short bf16x8 __attribute__((ext_vector_type(8)));
typedef float f32x4  __attribute__((ext_vector_type(4)));

// RNE float->bf16 and back (finite data only)
__device__ inline unsigned short f2bf(float f)
{
    unsigned u = __float_as_uint(f);
    return (unsigned short)((u + 0x7FFFu + ((u >> 16) & 1u)) >> 16);
}
__device__ inline float bf2f(unsigned short h)
{
    return __uint_as_float((unsigned)h << 16);
}
__device__ inline void split3(float f, unsigned short& h,
                              unsigned short& m, unsigned short& l)
{
    h = f2bf(f);
    float r1 = f - bf2f(h);
    m = f2bf(r1);
    l = f2bf(r1 - bf2f(m));
}

// 6-term bf16x3 product accumulate (fixed order: small terms first)
__device__ inline f32x4 mfma6(bf16x8 ah, bf16x8 am, bf16x8 al,
                              bf16x8 bh, bf16x8 bm, bf16x8 bl, f32x4 a)
{
    a = __builtin_amdgcn_mfma_f32_16x16x32_bf16(al, bh, a, 0, 0, 0);
    a = __builtin_amdgcn_mfma_f32_16x16x32_bf16(ah, bl, a, 0, 0, 0);
    a = __builtin_amdgcn_mfma_f32_16x16x32_bf16(am, bm, a, 0, 0, 0);
    a = __builtin_amdgcn_mfma_f32_16x16x32_bf16(am, bh, a, 0, 0, 0);
    a = __builtin_amdgcn_mfma_f32_16x16x32_bf16(ah, bm, a, 0, 0, 0);
    a = __builtin_amdgcn_mfma_f32_16x16x32_bf16(ah, bh, a, 0, 0, 0);
    return a;
}

// ---------------------------------------------------------------
// Prep: split x [1024][768] into 3 bf16 components.
// ---------------------------------------------------------------
__global__ __launch_bounds__(256) void split_x_kernel(
    const float* __restrict__ x, unsigned short* __restrict__ xh,
    unsigned short* __restrict__ xm, unsigned short* __restrict__ xl)
{
    const int idx = (blockIdx.x * 256 + threadIdx.x) * 4;
    float4 v = *(const float4*)(x + idx);
    float vv[4] = {v.x, v.y, v.z, v.w};
    unsigned short h[4], m[4], l[4];
    #pragma unroll
    for (int e = 0; e < 4; ++e) split3(vv[e], h[e], m[e], l[e]);
    *(ushort4*)(xh + idx) = make_ushort4(h[0], h[1], h[2], h[3]);
    *(ushort4*)(xm + idx) = make_ushort4(m[0], m[1], m[2], m[3]);
    *(ushort4*)(xl + idx) = make_ushort4(l[0], l[1], l[2], l[3]);
}

// ---------------------------------------------------------------
// Prep: transpose w [768][ncols] -> [ncols][768] + split to 3 comps.
// ---------------------------------------------------------------
__global__ __launch_bounds__(256) void tsplit_kernel(
    const float* __restrict__ w, int ncols, unsigned short* __restrict__ wh,
    unsigned short* __restrict__ wm, unsigned short* __restrict__ wl)
{
    __shared__ float T[64][65];
    const int c0 = blockIdx.x * 64;
    const int k0 = blockIdx.y * 64;
    const int tid = threadIdx.x;
    #pragma unroll
    for (int i = 0; i < 16; ++i) {
        int idx = tid + i * 256;
        int kk = idx >> 6, cc = idx & 63;
        T[kk][cc] = w[(size_t)(k0 + kk) * ncols + c0 + cc];
    }
    __syncthreads();
    #pragma unroll
    for (int i = 0; i < 16; ++i) {
        int idx = tid + i * 256;
        int col = idx >> 6, kk = idx & 63;
        unsigned short h, m, l;
        split3(T[kk][col], h, m, l);
        size_t o = (size_t)(c0 + col) * CDIM + k0 + kk;
        wh[o] = h; wm[o] = m; wl[o] = l;
    }
}

// ---------------------------------------------------------------
// Prep: split y (head layout) gathered to [1024][768] comps.
// ---------------------------------------------------------------
__global__ __launch_bounds__(256) void split_y_kernel(
    const float* __restrict__ y, unsigned short* __restrict__ yh,
    unsigned short* __restrict__ ym, unsigned short* __restrict__ yl)
{
    const int fl = (blockIdx.x * 256 + threadIdx.x) * 4;
    const int m = fl / CDIM;
    const int c0 = fl - m * CDIM;
    const int b_ = m >> 9, t = m & 511;
    const int hh = c0 >> 6, d = c0 & 63;
    float4 v = *(const float4*)(y + ((((size_t)b_ * NHEAD + hh) * SEQ) + t) * HDIM + d);
    float vv[4] = {v.x, v.y, v.z, v.w};
    unsigned short h[4], mm[4], l[4];
    #pragma unroll
    for (int e = 0; e < 4; ++e) split3(vv[e], h[e], mm[e], l[e]);
    *(ushort4*)(yh + fl) = make_ushort4(h[0], h[1], h[2], h[3]);
    *(ushort4*)(ym + fl) = make_ushort4(mm[0], mm[1], mm[2], mm[3]);
    *(ushort4*)(yl + fl) = make_ushort4(l[0], l[1], l[2], l[3]);
}

// ---------------------------------------------------------------
// Kernel 1: QKV GEMM, bf16x3 MFMA, LDS-FREE (fragments are 16B
// contiguous global loads; no barriers -> deep pipelining).
// 32x64 tile, 1 wave, K=768. Epilogue: q/k written as bf16x3
// comps (fp32 q/k dead after qkkt), v as fp32.
// ---------------------------------------------------------------
__global__ __launch_bounds__(64) void qkv_mfma_kernel(
    const unsigned short* __restrict__ xh, const unsigned short* __restrict__ xm,
    const unsigned short* __restrict__ xl, const unsigned short* __restrict__ wh,
    const unsigned short* __restrict__ wm, const unsigned short* __restrict__ wl,
    const float* __restrict__ bias,
    unsigned short* __restrict__ qh, unsigned short* __restrict__ qm,
    unsigned short* __restrict__ ql, unsigned short* __restrict__ kh,
    unsigned short* __restrict__ km, unsigned short* __restrict__ kl,
    float* __restrict__ v)
{
    const int bn = blockIdx.x * 64;
    const int bm = blockIdx.y * 32;
    const int lane = threadIdx.x;
    const int lrow = lane & 15;
    const int lk8 = (lane >> 4) << 3;

    f32x4 acc[2][4];
    #pragma unroll
    for (int a = 0; a < 2; ++a)
        #pragma unroll
        for (int b = 0; b < 4; ++b) acc[a][b] = (f32x4){0.f, 0.f, 0.f, 0.f};

    for (int k0 = 0; k0 < CDIM; k0 += 32) {
        bf16x8 af[3][2], bf[3][4];
        #pragma unroll
        for (int mi = 0; mi < 2; ++mi) {
            size_t ro = (size_t)(bm + mi * 16 + lrow) * CDIM + k0 + lk8;
            af[0][mi] = *(const bf16x8*)(xh + ro);
            af[1][mi] = *(const bf16x8*)(xm + ro);
            af[2][mi] = *(const bf16x8*)(xl + ro);
        }
        #pragma unroll
        for (int ni = 0; ni < 4; ++ni) {
            size_t ro = (size_t)(bn + ni * 16 + lrow) * CDIM + k0 + lk8;
            bf[0][ni] = *(const bf16x8*)(wh + ro);
            bf[1][ni] = *(const bf16x8*)(wm + ro);
            bf[2][ni] = *(const bf16x8*)(wl + ro);
        }
        #pragma unroll
        for (int mi = 0; mi < 2; ++mi)
            #pragma unroll
            for (int ni = 0; ni < 4; ++ni)
                acc[mi][ni] = mfma6(af[0][mi], af[1][mi], af[2][mi],
                                    bf[0][ni], bf[1][ni], bf[2][ni], acc[mi][ni]);
    }

    const int rbase = (lane >> 4) << 2;
    #pragma unroll
    for (int mi = 0; mi < 2; ++mi) {
        #pragma unroll
        for (int ni = 0; ni < 4; ++ni) {
            int cc = bn + ni * 16 + lrow;
            float bval = bias[cc];
            int part = cc / CDIM;
            int c2 = cc - part * CDIM;
            int hh = c2 >> 6, d = c2 & 63;
            #pragma unroll
            for (int r = 0; r < 4; ++r) {
                int m = bm + mi * 16 + rbase + r;
                int b_ = m >> 9, t = m & 511;
                size_t off = ((((size_t)b_ * NHEAD + hh) * SEQ) + t) * HDIM + d;
                float val = acc[mi][ni][r] + bval;
                if (part == 2) {
                    v[off] = val;
                } else {
                    unsigned short h2, m2, l2;
                    split3(val, h2, m2, l2);
                    if (part == 0) { qh[off] = h2; qm[off] = m2; ql[off] = l2; }
                    else           { kh[off] = h2; km[off] = m2; kl[off] = l2; }
                }
            }
        }
    }
}

// ---------------------------------------------------------------
// Kernel 2: S (z=0) and KKT (z=1) via bf16x3 MFMA, LDS-free.
// 64x64 lower-tri tiles per head, K=64 (2 ksteps).
// ---------------------------------------------------------------
__global__ __launch_bounds__(64) void qkkt_mfma_kernel(
    const unsigned short* __restrict__ qh, const unsigned short* __restrict__ qm,
    const unsigned short* __restrict__ ql, const unsigned short* __restrict__ kh,
    const unsigned short* __restrict__ km, const unsigned short* __restrict__ kl,
    float* __restrict__ S, float* __restrict__ KKT)
{
    const int e = blockIdx.x;
    const int n = blockIdx.y;
    const int z = blockIdx.z;     // 0 -> S (A=Q), 1 -> KKT (A=K)
    int it = 0, start = 0;
    while (start + it + 1 <= e) { start += it + 1; ++it; }
    const int jt = e - start;
    const int lane = threadIdx.x;
    const int lrow = lane & 15;
    const int lk8 = (lane >> 4) << 3;
    const size_t base = (size_t)n * SEQ * HDIM;

    const unsigned short* A0 = z ? kh : qh;
    const unsigned short* A1 = z ? km : qm;
    const unsigned short* A2 = z ? kl : ql;

    f32x4 acc[4][4];
    #pragma unroll
    for (int a = 0; a < 4; ++a)
        #pragma unroll
        for (int b = 0; b < 4; ++b) acc[a][b] = (f32x4){0.f, 0.f, 0.f, 0.f};

    #pragma unroll
    for (int ks = 0; ks < 2; ++ks) {
        const int k0 = ks * 32;
        bf16x8 af[3][4], bf[3][4];
        #pragma unroll
        for (int mi = 0; mi < 4; ++mi) {
            size_t ro = base + (size_t)(it * 64 + mi * 16 + lrow) * HDIM + k0 + lk8;
            af[0][mi] = *(const bf16x8*)(A0 + ro);
            af[1][mi] = *(const bf16x8*)(A1 + ro);
            af[2][mi] = *(const bf16x8*)(A2 + ro);
        }
        #pragma unroll
        for (int ni = 0; ni < 4; ++ni) {
            size_t ro = base + (size_t)(jt * 64 + ni * 16 + lrow) * HDIM + k0 + lk8;
            bf[0][ni] = *(const bf16x8*)(kh + ro);
            bf[1][ni] = *(const bf16x8*)(km + ro);
            bf[2][ni] = *(const bf16x8*)(kl + ro);
        }
        #pragma unroll
        for (int mi = 0; mi < 4; ++mi)
            #pragma unroll
            for (int ni = 0; ni < 4; ++ni)
                acc[mi][ni] = mfma6(af[0][mi], af[1][mi], af[2][mi],
                                    bf[0][ni], bf[1][ni], bf[2][ni], acc[mi][ni]);
    }

    const int rbase = (lane >> 4) << 2;
    if (z == 0) {
        #pragma unroll
        for (int mi = 0; mi < 4; ++mi)
            #pragma unroll
            for (int ni = 0; ni < 4; ++ni) {
                int col = jt * 64 + ni * 16 + lrow;
                #pragma unroll
                for (int r = 0; r < 4; ++r) {
                    int row = it * 64 + mi * 16 + rbase + r;
                    S[((size_t)n * SEQ + row) * SEQ + col] = acc[mi][ni][r];
                }
            }
    } else {
        float* gdst = KKT + ((size_t)n * 36 + e) * 4096;
        #pragma unroll
        for (int mi = 0; mi < 4; ++mi)
            #pragma unroll
            for (int ni = 0; ni < 4; ++ni) {
                int col = ni * 16 + lrow;
                #pragma unroll
                for (int r = 0; r < 4; ++r)
                    gdst[(mi * 16 + rbase + r) * 64 + col] = acc[mi][ni][r];
            }
    }
}

// hybrid log: exact exponent + hardware f32 log2 of mantissa.
__device__ inline double hybrid_log(double a)
{
    unsigned long long b = __double_as_longlong(a);
    int e2 = (int)((b >> 52) & 0x7FF) - 1022;
    double m = __longlong_as_double((b & 0x000FFFFFFFFFFFFFULL) |
                                    0x3FE0000000000000ULL);
    return ((double)__log2f((float)m) + (double)e2) * 0.6931471805599453;
}

__device__ inline double rsqrt64(double x)
{
    double r = (double)rsqrtf((float)x);
    r = r * (1.5 - 0.5 * x * r * r);
    return r;
}

#define CSW(a, b)                                                        \
    {                                                                    \
        bool sw = (v##a < v##b) || ((v##a == v##b) && (j##a > j##b));    \
        float tf = sw ? v##b : v##a;                                     \
        float uf = sw ? v##a : v##b;                                     \
        int ti = sw ? j##b : j##a;                                       \
        int ui = sw ? j##a : j##b;                                       \
        v##a = tf; v##b = uf; j##a = ti; j##b = ui;                      \
    }

// ---------------------------------------------------------------
// Kernel 3: per-token DPP (unchanged).
// ---------------------------------------------------------------
__global__ __launch_bounds__(128) void dpp_kernel(
    const float* __restrict__ v, float* __restrict__ S,
    const float* __restrict__ KKT, const float* __restrict__ gate_p,
    float* __restrict__ y, float* __restrict__ denomArr)
{
    const int tid  = threadIdx.x;
    const int wid  = tid >> 6;
    const int lane = tid & 63;
    const int i = blockIdx.x * 2 + wid;
    const int n = blockIdx.y;
    const float* vh = v + (size_t)n * SEQ * HDIM;
    const float* KKTh = KKT + (size_t)n * 36 * 4096;
    float* Srow = S + ((size_t)n * SEQ + i) * SEQ;

    __shared__ float prow[2][SEQ];
    __shared__ float gramf[2][17][17];
    __shared__ int   eidx[2][17];
    __shared__ int   selS[2][SMAX];

    float sim8[8];
    #pragma unroll
    for (int m = 0; m < 8; ++m) {
        int j = lane + (m << 6);
        sim8[m] = (j <= i) ? Srow[j] : NEGINF;
    }
    if (lane < SMAX) selS[wid][lane] = i;

    {
        float v0 = sim8[0], v1 = sim8[1], v2 = sim8[2], v3 = sim8[3],
              v4 = sim8[4], v5 = sim8[5], v6 = sim8[6], v7 = sim8[7];
        int j0 = lane, j1 = lane + 64, j2 = lane + 128, j3 = lane + 192,
            j4 = lane + 256, j5 = lane + 320, j6 = lane + 384, j7 = lane + 448;
        CSW(0, 1) CSW(2, 3) CSW(4, 5) CSW(6, 7)
        CSW(0, 2) CSW(1, 3) CSW(4, 6) CSW(5, 7)
        CSW(1, 2) CSW(5, 6)
        CSW(0, 4) CSW(1, 5) CSW(2, 6) CSW(3, 7)
        CSW(2, 4) CSW(3, 5)
        CSW(1, 2) CSW(3, 4) CSW(5, 6)

        if (lane == 0) eidx[wid][0] = i;
        #pragma unroll
        for (int s = 0; s < TOPM; ++s) {
            float rv = v0;
            #pragma unroll
            for (int off = 32; off; off >>= 1)
                rv = fmaxf(rv, __shfl_xor(rv, off));
            unsigned long long tied = __ballot(v0 == rv);
            int ri;
            if (__popcll(tied) == 1) {
                ri = __shfl(j0, (int)__builtin_ctzll(tied));
            } else {
                int cnd = (v0 == rv) ? j0 : 0x7FFFFFFF;
                #pragma unroll
                for (int off = 32; off; off >>= 1)
                    cnd = min(cnd, __shfl_xor(cnd, off));
                ri = cnd;
            }
            if (lane == 0) eidx[wid][1 + s] = ri;
            if (v0 == rv && j0 == ri) {
                v0 = v1; j0 = j1; v1 = v2; j1 = j2; v2 = v3; j2 = j3;
                v3 = v4; j3 = j4; v4 = v5; j4 = j5; v5 = v6; j5 = j6;
                v6 = v7; j6 = j7; v7 = -3e38f; j7 = 1023;
            }
        }
    }

    const float scale = 0.125f;
    float lm = -3e38f;
    #pragma unroll
    for (int m = 0; m < 8; ++m) lm = fmaxf(lm, sim8[m]);
    #pragma unroll
    for (int off = 32; off; off >>= 1) lm = fmaxf(lm, __shfl_xor(lm, off));
    const float mx = lm * scale;
    float sum = 0.f;
    #pragma unroll
    for (int m = 0; m < 8; ++m) {
        float p = expf(sim8[m] * scale - mx);
        int j = lane + (m << 6);
        prow[wid][j] = p;
        Srow[j] = p;
        sum += p;
    }
    #pragma unroll
    for (int off = 32; off; off >>= 1) sum += __shfl_xor(sum, off);
    const float denom = sum;
    asm volatile("s_waitcnt lgkmcnt(0)" ::: "memory");

    for (int e = lane; e < 153; e += 64) {
        int a = (int)((sqrtf(8.f * (float)e + 1.f) - 1.f) * 0.5f);
        int st = (a * (a + 1)) >> 1;
        if (st > e) { --a; st = (a * (a + 1)) >> 1; }
        else if (st + a + 1 <= e) { ++a; st = (a * (a + 1)) >> 1; }
        int b = e - st;
        int ra = eidx[wid][a], rb = eidx[wid][b];
        int row = ra > rb ? ra : rb;
        int col = ra > rb ? rb : ra;
        int itt = row >> 6, jtt = col >> 6;
        int p = ((itt * (itt + 1)) >> 1) + jtt;
        float s = KKTh[((size_t)p * 64 + (row & 63)) * 64 + (col & 63)];
        gramf[wid][a][b] = s;
        gramf[wid][b][a] = s;
    }
    asm volatile("s_waitcnt lgkmcnt(0)" ::: "memory");

    int sc = 1;
    {
        const int c = lane;
        const bool isCand = (c < TOPM);
        const int nvalid = (i + 1 < TOPM) ? (i + 1) : TOPM;
        bool active = isCand && (c < nvalid) && (eidx[wid][1 + c] != i);
        double zc[7];
        #pragma unroll
        for (int t = 0; t < 7; ++t) zc[t] = 0.0;
        double det = (double)gramf[wid][0][0];
        double cur = 0.0;
        double invL00 = rsqrt64(det > 0.0 ? det : 1e-30);
        double dcv = 0.0;
        if (isCand) {
            zc[0] = (double)gramf[wid][1 + c][0] * invL00;
            dcv = (double)gramf[wid][1 + c][1 + c] - zc[0] * zc[0];
        }

        for (int it2 = 0; it2 < SMAX - 1; ++it2) {
            double argc = det * dcv + 1e-6;
            double key = active ? (argc > 0.0 ? argc : 1e300) : -1.0;
            int rc = c;
            #pragma unroll
            for (int off = 1; off <= 8; off <<= 1) {
                double ov = __shfl_xor(key, off);
                int    oc = __shfl_xor(rc, off);
                if (ov > key || (ov == key && oc < rc)) { key = ov; rc = oc; }
            }
            rc = __shfl(rc, 0);
            bool any = (__any(active ? 1 : 0) != 0);
            double dbest = __shfl(dcv, rc);
            bool take;
            if (it2 < 2) {
                take = any;
            } else {
                double argb = det * dbest + 1e-6;
                bool pos = argb > 0.0;
                double score = hybrid_log(pos ? argb : 1.0) / (double)(sc + 1);
                take = any && (it2 < 3 || (pos && score > cur));
                if (take) cur = pos ? score : __builtin_nan("");
            }
            if (!take) break;

            double invLss = rsqrt64(dbest > 1e-30 ? dbest : 1e-30);
            double zb[7];
            #pragma unroll
            for (int t = 0; t < 7; ++t) zb[t] = __shfl(zc[t], rc);
            if (isCand) {
                double crossn = (double)gramf[wid][1 + c][1 + rc];
                double s2 = 0.0;
                #pragma unroll
                for (int t = 0; t < 7; ++t) s2 += zc[t] * zb[t];
                double znew = (crossn - s2) * invLss;
                #pragma unroll
                for (int t = 0; t < 7; ++t) if (t == sc) zc[t] = znew;
                dcv -= znew * znew;
            }
            det = det * dbest;
            if (c == rc) active = false;
            if (lane == 0) selS[wid][sc] = eidx[wid][1 + rc];
            ++sc;
        }
    }

    int selI[SMAX];
    #pragma unroll
    for (int s = 0; s < SMAX; ++s) selI[s] = selS[wid][s];
    float wsum = 0.f;
    #pragma unroll
    for (int s = 0; s < SMAX; ++s) if (s < sc) wsum += prow[wid][selI[s]];
    float yd = 0.f;
    #pragma unroll
    for (int s = 0; s < SMAX; ++s)
        if (s < sc) yd = fmaf(prow[wid][selI[s]], vh[selI[s] * HDIM + lane], yd);
    const float gp = gate_p[0];
    const float gate = 1.f / (1.f + expf(-gp));
    y[((size_t)n * SEQ + i) * HDIM + lane] = gate * yd / wsum;
    if (lane == 0) denomArr[n * SEQ + i] = denom;
}

// ---------------------------------------------------------------
// Kernel 4: y += (1-gate) * (P @ V)/denom (unchanged).
// ---------------------------------------------------------------
__global__ __launch_bounds__(256) void pv_gemm_kernel(
    const float* __restrict__ P, const float* __restrict__ v,
    const float* __restrict__ denomArr, const float* __restrict__ gate_p,
    float* __restrict__ y)
{
    __shared__ float Ps[32][36];
    __shared__ float Vs[32][68];
    const int tt = blockIdx.x;
    const int n  = blockIdx.y;
    const int t0 = tt * 32;
    const int tid = threadIdx.x;
    const float* Ph = P + (size_t)n * SEQ * SEQ;
    const float* vh = v + (size_t)n * SEQ * HDIM;
    const int tm = (tid >> 4) << 1;
    const int tn = (tid & 15) << 2;
    float acc[2][4] = {};
    const int jmax = t0 + 32;
    for (int j0 = 0; j0 < jmax; j0 += 32) {
        {
            int tok = tid >> 3, j4 = (tid & 7) << 2;
            *(float4*)&Ps[tok][j4] =
                *(const float4*)(Ph + (t0 + tok) * SEQ + j0 + j4);
        }
        #pragma unroll
        for (int l = 0; l < 2; ++l) {
            int idx = tid + l * 256;
            int j = idx >> 4, d4 = (idx & 15) << 2;
            *(float4*)&Vs[j][d4] = *(const float4*)(vh + (j0 + j) * HDIM + d4);
        }
        __syncthreads();
        #pragma unroll
        for (int j4 = 0; j4 < 8; ++j4) {
            float4 p0r = *(const float4*)&Ps[tm + 0][j4 << 2];
            float4 p1r = *(const float4*)&Ps[tm + 1][j4 << 2];
            float pr[2][4] = {{p0r.x, p0r.y, p0r.z, p0r.w},
                              {p1r.x, p1r.y, p1r.z, p1r.w}};
            #pragma unroll
            for (int l = 0; l < 4; ++l) {
                float4 v4 = *(const float4*)&Vs[(j4 << 2) + l][tn];
                float vv[4] = {v4.x, v4.y, v4.z, v4.w};
                #pragma unroll
                for (int u = 0; u < 2; ++u)
                    #pragma unroll
                    for (int w2 = 0; w2 < 4; ++w2)
                        acc[u][w2] = fmaf(pr[u][l], vv[w2], acc[u][w2]);
            }
        }
        __syncthreads();
    }
    const float gp = gate_p[0];
    const float gate = 1.f / (1.f + expf(-gp));
    #pragma unroll
    for (int u = 0; u < 2; ++u) {
        int i = t0 + tm + u;
        float den = denomArr[n * SEQ + i];
        #pragma unroll
        for (int w2 = 0; w2 < 4; ++w2) {
            int d = tn + w2;
            size_t off = ((size_t)n * SEQ + i) * HDIM + d;
            y[off] += (1.f - gate) * acc[u][w2] / den;
        }
    }
}

// ---------------------------------------------------------------
// Kernel 5: proj GEMM, bf16x3 MFMA, LDS-free, 32x64 tile, K=768,
// bias fused (no K-split, no reduce).
// ---------------------------------------------------------------
__global__ __launch_bounds__(64) void proj_mfma_kernel(
    const unsigned short* __restrict__ ah, const unsigned short* __restrict__ am,
    const unsigned short* __restrict__ al, const unsigned short* __restrict__ bh,
    const unsigned short* __restrict__ bm2, const unsigned short* __restrict__ bl,
    const float* __restrict__ bias, float* __restrict__ out)
{
    const int bn = blockIdx.x * 64;
    const int bmr = blockIdx.y * 32;
    const int lane = threadIdx.x;
    const int lrow = lane & 15;
    const int lk8 = (lane >> 4) << 3;

    f32x4 acc[2][4];
    #pragma unroll
    for (int a = 0; a < 2; ++a)
        #pragma unroll
        for (int b = 0; b < 4; ++b) acc[a][b] = (f32x4){0.f, 0.f, 0.f, 0.f};

    for (int k0 = 0; k0 < CDIM; k0 += 32) {
        bf16x8 af[3][2], bf[3][4];
        #pragma unroll
        for (int mi = 0; mi < 2; ++mi) {
            size_t ro = (size_t)(bmr + mi * 16 + lrow) * CDIM + k0 + lk8;
            af[0][mi] = *(const bf16x8*)(ah + ro);
            af[1][mi] = *(const bf16x8*)(am + ro);
            af[2][mi] = *(const bf16x8*)(al + ro);
        }
        #pragma unroll
        for (int ni = 0; ni < 4; ++ni) {
            size_t ro = (size_t)(bn + ni * 16 + lrow) * CDIM + k0 + lk8;
            bf[0][ni] = *(const bf16x8*)(bh + ro);
            bf[1][ni] = *(const bf16x8*)(bm2 + ro);
            bf[2][ni] = *(const bf16x8*)(bl + ro);
        }
        #pragma unroll
        for (int mi = 0; mi < 2; ++mi)
            #pragma unroll
            for (int ni = 0; ni < 4; ++ni)
                acc[mi][ni] = mfma6(af[0][mi], af[1][mi], af[2][mi],
                                    bf[0][ni], bf[1][ni], bf[2][ni], acc[mi][ni]);
    }

    const int rbase = (lane >> 4) << 2;
    #pragma unroll
    for (int mi = 0; mi < 2; ++mi)
        #pragma unroll
        for (int ni = 0; ni < 4; ++ni) {
            int cc = bn + ni * 16 + lrow;
            float bval = bias[cc];
            #pragma unroll
            for (int r = 0; r < 4; ++r) {
                int m = bmr + mi * 16 + rbase + r;
                out[(size_t)m * CDIM + cc] = acc[mi][ni][r] + bval;
            }
        }
}

extern "C" void kernel_launch(void* const* d_in, const int* in_sizes, int n_in,
                              void* d_out, int out_size, void* d_ws, size_t ws_size,
                              hipStream_t stream)
{
    const float* x      = (const float*)d_in[0];
    const float* w_qkv  = (const float*)d_in[1];
    const float* b_qkv  = (const float*)d_in[2];
    const float* w_proj = (const float*)d_in[3];
    const float* b_proj = (const float*)d_in[4];
    const float* gate_p = (const float*)d_in[5];
    float* out = (float*)d_out;

    float* ws = (float*)d_ws;
    const size_t HS = (size_t)NBATCH * NHEAD * SEQ * HDIM;   // 786432
    const size_t SS = (size_t)NBATCH * NHEAD * SEQ * SEQ;    // 6291456

    // Layout (floats): [qk-comps / y : 3*HS][v : HS][S : SS][den][KKT]
    unsigned short* cb = (unsigned short*)ws;       // 6*HS ushorts = 3*HS floats
    unsigned short* qh = cb;
    unsigned short* qm = cb + HS;
    unsigned short* ql = cb + 2 * HS;
    unsigned short* kh = cb + 3 * HS;
    unsigned short* km = cb + 4 * HS;
    unsigned short* kl = cb + 5 * HS;
    float* y   = ws + 2 * HS;        // overlaps km/kl: dead after qkkt
    float* v   = ws + 3 * HS;
    float* S   = ws + 4 * HS;
    float* den = S + SS;
    float* KKT = den + 16384;

    // x comps + w_qkv^T comps live in S region (free until qkkt).
    unsigned short* us = (unsigned short*)S;
    unsigned short* xh = us;
    unsigned short* xm = us + HS;
    unsigned short* xl = us + 2 * HS;
    unsigned short* wqh = us + 3 * HS;
    unsigned short* wqm = us + 3 * HS + 1769472;
    unsigned short* wql = us + 3 * HS + 2 * 1769472;   // 7.67M ush < 12.58M

    // y comps + w_proj^T comps live in S region (free after pv).
    unsigned short* yh = us;
    unsigned short* ym = us + HS;
    unsigned short* yl = us + 2 * HS;
    unsigned short* wph = us + 3 * HS;
    unsigned short* wpm = us + 3 * HS + 589824;
    unsigned short* wpl = us + 3 * HS + 2 * 589824;

    split_x_kernel<<<768, 256, 0, stream>>>(x, xh, xm, xl);
    tsplit_kernel<<<dim3(36, 12), 256, 0, stream>>>(w_qkv, 3 * CDIM, wqh, wqm, wql);
    qkv_mfma_kernel<<<dim3(36, 32), 64, 0, stream>>>(
        xh, xm, xl, wqh, wqm, wql, b_qkv, qh, qm, ql, kh, km, kl, v);
    qkkt_mfma_kernel<<<dim3(36, NBATCH * NHEAD, 2), 64, 0, stream>>>(
        qh, qm, ql, kh, km, kl, S, KKT);
    dpp_kernel<<<dim3(SEQ / 2, NBATCH * NHEAD), 128, 0, stream>>>(
        v, S, KKT, gate_p, y, den);
    pv_gemm_kernel<<<dim3(SEQ / 32, NBATCH * NHEAD), 256, 0, stream>>>(
        S, v, den, gate_p, y);
    split_y_kernel<<<768, 256, 0, stream>>>(y, yh, ym, yl);
    tsplit_kernel<<<dim3(12, 12), 256, 0, stream>>>(w_proj, CDIM, wph, wpm, wpl);
    proj_mfma_kernel<<<dim3(12, 32), 64, 0, stream>>>(
        yh, ym, yl, wph, wpm, wpl, b_proj, out);
}

// Round 18
// 169.829 us; speedup vs baseline: 1.2710x; 1.2710x over previous
//
#include <hip/hip_runtime.h>
#include <math.h>

// Problem constants
constexpr int SEQ   = 512;
constexpr int HDIM  = 64;
constexpr int NHEAD = 12;
constexpr int NBATCH = 2;
constexpr int CDIM  = 768;
constexpr int TOPM  = 16;
constexpr int SMAX  = 8;
constexpr float NEGINF = -1e30f;

typedef short bf16x8 __attribute__((ext_vector_type(8)));
typedef float f32x4  __attribute__((ext_vector_type(4)));

// async global->LDS, 16B per lane, wave-uniform LDS base
__device__ inline void gload_lds16(const void* src, void* lds_base)
{
    __builtin_amdgcn_global_load_lds(
        (const __attribute__((address_space(1))) void*)src,
        (__attribute__((address_space(3))) void*)lds_base, 16, 0, 0);
}

// RNE float->bf16 and back (finite data only)
__device__ inline unsigned short f2bf(float f)
{
    unsigned u = __float_as_uint(f);
    return (unsigned short)((u + 0x7FFFu + ((u >> 16) & 1u)) >> 16);
}
__device__ inline float bf2f(unsigned short h)
{
    return __uint_as_float((unsigned)h << 16);
}

// ---------------------------------------------------------------
// Prep 1: split x [1024][768] into 3 bf16 components (hi/mid/lo).
// ---------------------------------------------------------------
__global__ __launch_bounds__(256) void split_x_kernel(
    const float* __restrict__ x, unsigned short* __restrict__ xh,
    unsigned short* __restrict__ xm, unsigned short* __restrict__ xl)
{
    const int idx = (blockIdx.x * 256 + threadIdx.x) * 4;
    float4 v = *(const float4*)(x + idx);
    float vv[4] = {v.x, v.y, v.z, v.w};
    unsigned short h[4], m[4], l[4];
    #pragma unroll
    for (int e = 0; e < 4; ++e) {
        float f = vv[e];
        unsigned short bh = f2bf(f);
        float r1 = f - bf2f(bh);
        unsigned short bm2 = f2bf(r1);
        float r2 = r1 - bf2f(bm2);
        h[e] = bh; m[e] = bm2; l[e] = f2bf(r2);
    }
    *(ushort4*)(xh + idx) = make_ushort4(h[0], h[1], h[2], h[3]);
    *(ushort4*)(xm + idx) = make_ushort4(m[0], m[1], m[2], m[3]);
    *(ushort4*)(xl + idx) = make_ushort4(l[0], l[1], l[2], l[3]);
}

// ---------------------------------------------------------------
// Prep 2: transpose w_qkv [768][2304] -> [2304][768] and split to
// 3 bf16 components. 64x64 LDS tile transpose.
// ---------------------------------------------------------------
__global__ __launch_bounds__(256) void tsplit_w_kernel(
    const float* __restrict__ w, unsigned short* __restrict__ wh,
    unsigned short* __restrict__ wm, unsigned short* __restrict__ wl)
{
    __shared__ float T[64][65];
    const int c0 = blockIdx.x * 64;   // col tile (36)
    const int k0 = blockIdx.y * 64;   // k tile (12)
    const int tid = threadIdx.x;
    #pragma unroll
    for (int i = 0; i < 16; ++i) {
        int idx = tid + i * 256;
        int kk = idx >> 6, cc = idx & 63;
        T[kk][cc] = w[(size_t)(k0 + kk) * (3 * CDIM) + c0 + cc];
    }
    __syncthreads();
    #pragma unroll
    for (int i = 0; i < 16; ++i) {
        int idx = tid + i * 256;
        int col = idx >> 6, kk = idx & 63;
        float f = T[kk][col];
        unsigned short bh = f2bf(f);
        float r1 = f - bf2f(bh);
        unsigned short bm2 = f2bf(r1);
        float r2 = r1 - bf2f(bm2);
        size_t o = (size_t)(c0 + col) * CDIM + k0 + kk;
        wh[o] = bh; wm[o] = bm2; wl[o] = f2bf(r2);
    }
}

// ---------------------------------------------------------------
// Kernel 1: QKV GEMM via bf16x3 MFMA. 64x64 tile, FOUR waves (wave
// w owns the 16-row strip w*16..w*16+15), K=768, bias fused.
// LDS staging via global_load_lds (R15-proven layout); per-output
// 6-term ascending-K mfma chain identical to R15 -> bitwise-
// identical q/k/v.
// ---------------------------------------------------------------
__global__ __launch_bounds__(256) void qkv_mfma_kernel(
    const unsigned short* __restrict__ xh, const unsigned short* __restrict__ xm,
    const unsigned short* __restrict__ xl, const unsigned short* __restrict__ wh,
    const unsigned short* __restrict__ wm, const unsigned short* __restrict__ wl,
    const float* __restrict__ bias,
    float* __restrict__ q, float* __restrict__ k, float* __restrict__ v)
{
    __shared__ unsigned short As[3][64 * 32];
    __shared__ unsigned short Bs[3][64 * 32];
    const int bn = blockIdx.x * 64;
    const int bm = blockIdx.y * 64;
    const int tid = threadIdx.x;
    const int wid = tid >> 6;
    const int lane = tid & 63;
    const int lrow = lane & 15;
    const int lk8 = (lane >> 4) << 3;

    f32x4 acc[4];
    #pragma unroll
    for (int b = 0; b < 4; ++b) acc[b] = (f32x4){0.f, 0.f, 0.f, 0.f};

    const unsigned short* xs[3] = {xh, xm, xl};
    const unsigned short* wsrc[3] = {wh, wm, wl};

    // this block-thread's staging slot (16B granules): 0..255
    const int slot = wid * 64 + lane;
    const int srow = slot >> 2;
    const int sk8 = (slot & 3) << 3;

    for (int k0 = 0; k0 < CDIM; k0 += 32) {
        #pragma unroll
        for (int c = 0; c < 3; ++c)
            gload_lds16(xs[c] + (size_t)(bm + srow) * CDIM + k0 + sk8,
                        &As[c][wid * 512]);
        #pragma unroll
        for (int c = 0; c < 3; ++c)
            gload_lds16(wsrc[c] + (size_t)(bn + srow) * CDIM + k0 + sk8,
                        &Bs[c][wid * 512]);
        __syncthreads();   // drains vmcnt (gload_lds) before reads

        bf16x8 bf[3][4];
        #pragma unroll
        for (int c = 0; c < 3; ++c)
            #pragma unroll
            for (int ni = 0; ni < 4; ++ni)
                bf[c][ni] = *(const bf16x8*)&Bs[c][(ni * 16 + lrow) * 32 + lk8];

        bf16x8 ah = *(const bf16x8*)&As[0][(wid * 16 + lrow) * 32 + lk8];
        bf16x8 am = *(const bf16x8*)&As[1][(wid * 16 + lrow) * 32 + lk8];
        bf16x8 al = *(const bf16x8*)&As[2][(wid * 16 + lrow) * 32 + lk8];
        #pragma unroll
        for (int ni = 0; ni < 4; ++ni) {
            f32x4 a = acc[ni];
            a = __builtin_amdgcn_mfma_f32_16x16x32_bf16(al, bf[0][ni], a, 0, 0, 0);
            a = __builtin_amdgcn_mfma_f32_16x16x32_bf16(ah, bf[2][ni], a, 0, 0, 0);
            a = __builtin_amdgcn_mfma_f32_16x16x32_bf16(am, bf[1][ni], a, 0, 0, 0);
            a = __builtin_amdgcn_mfma_f32_16x16x32_bf16(am, bf[0][ni], a, 0, 0, 0);
            a = __builtin_amdgcn_mfma_f32_16x16x32_bf16(ah, bf[1][ni], a, 0, 0, 0);
            a = __builtin_amdgcn_mfma_f32_16x16x32_bf16(ah, bf[0][ni], a, 0, 0, 0);
            acc[ni] = a;
        }
        __syncthreads();
    }

    const int rbase = (lane >> 4) << 2;
    #pragma unroll
    for (int ni = 0; ni < 4; ++ni) {
        int cc = bn + ni * 16 + lrow;
        float bval = bias[cc];
        int part = cc / CDIM;
        int c2 = cc - part * CDIM;
        int hh = c2 >> 6, d = c2 & 63;
        float* dst = (part == 0) ? q : ((part == 1) ? k : v);
        #pragma unroll
        for (int r = 0; r < 4; ++r) {
            int m = bm + wid * 16 + rbase + r;
            int b_ = m >> 9, t = m & 511;
            dst[((((size_t)b_ * NHEAD + hh) * SEQ) + t) * HDIM + d] =
                acc[ni][r] + bval;
        }
    }
}

// ---------------------------------------------------------------
// Kernel 2: fused S = QK^T and KKT (unchanged, fp32).
// ---------------------------------------------------------------
__global__ __launch_bounds__(256) void qkkt_kernel(
    const float* __restrict__ q, const float* __restrict__ k,
    float* __restrict__ S, float* __restrict__ KKT)
{
    __shared__ float Qs[64][68];
    __shared__ float Ka[64][68];
    __shared__ float Kb[64][68];
    const int e = blockIdx.x;
    const int n = blockIdx.y;
    int it = 0, start = 0;
    while (start + it + 1 <= e) { start += it + 1; ++it; }
    const int jt = e - start;
    const int tid = threadIdx.x;
    const float* qh = q + (size_t)n * SEQ * HDIM;
    const float* kh = k + (size_t)n * SEQ * HDIM;

    #pragma unroll
    for (int l = 0; l < 4; ++l) {
        int idx = tid + l * 256;
        int tok = idx >> 4, d4 = (idx & 15) << 2;
        *(float4*)&Qs[tok][d4] = *(const float4*)(qh + (it * 64 + tok) * HDIM + d4);
        *(float4*)&Ka[tok][d4] = *(const float4*)(kh + (it * 64 + tok) * HDIM + d4);
        *(float4*)&Kb[tok][d4] = *(const float4*)(kh + (jt * 64 + tok) * HDIM + d4);
    }
    __syncthreads();

    const int tm = (tid >> 4) << 2;
    const int tn = (tid & 15) << 2;
    float sacc[4][4] = {};
    float gacc[4][4] = {};
    #pragma unroll 4
    for (int d4 = 0; d4 < 16; ++d4) {
        float4 qr[4], ar[4], br[4];
        #pragma unroll
        for (int u = 0; u < 4; ++u) {
            qr[u] = *(const float4*)&Qs[tm + u][d4 << 2];
            ar[u] = *(const float4*)&Ka[tm + u][d4 << 2];
        }
        #pragma unroll
        for (int w2 = 0; w2 < 4; ++w2)
            br[w2] = *(const float4*)&Kb[tn + w2][d4 << 2];
        #pragma unroll
        for (int u = 0; u < 4; ++u)
            #pragma unroll
            for (int w2 = 0; w2 < 4; ++w2) {
                float s = sacc[u][w2];
                s = fmaf(qr[u].x, br[w2].x, s);
                s = fmaf(qr[u].y, br[w2].y, s);
                s = fmaf(qr[u].z, br[w2].z, s);
                s = fmaf(qr[u].w, br[w2].w, s);
                sacc[u][w2] = s;
                float g = gacc[u][w2];
                g = fmaf(ar[u].x, br[w2].x, g);
                g = fmaf(ar[u].y, br[w2].y, g);
                g = fmaf(ar[u].z, br[w2].z, g);
                g = fmaf(ar[u].w, br[w2].w, g);
                gacc[u][w2] = g;
            }
    }
    float* gdst = KKT + ((size_t)n * 36 + e) * 4096;
    #pragma unroll
    for (int u = 0; u < 4; ++u) {
        int i = it * 64 + tm + u;
        float4 o = {sacc[u][0], sacc[u][1], sacc[u][2], sacc[u][3]};
        *(float4*)(S + ((size_t)n * SEQ + i) * SEQ + jt * 64 + tn) = o;
        float4 g = {gacc[u][0], gacc[u][1], gacc[u][2], gacc[u][3]};
        *(float4*)(gdst + (tm + u) * 64 + tn) = g;
    }
}

// hybrid log: exact exponent + hardware f32 log2 of mantissa.
__device__ inline double hybrid_log(double a)
{
    unsigned long long b = __double_as_longlong(a);
    int e2 = (int)((b >> 52) & 0x7FF) - 1022;
    double m = __longlong_as_double((b & 0x000FFFFFFFFFFFFFULL) |
                                    0x3FE0000000000000ULL);   // [0.5,1)
    return ((double)__log2f((float)m) + (double)e2) * 0.6931471805599453;
}

// 1/sqrt(x) via f32 rsqrt + one f64 Newton step (rel err ~1.5e-14).
__device__ inline double rsqrt64(double x)
{
    double r = (double)rsqrtf((float)x);
    r = r * (1.5 - 0.5 * x * r * r);
    return r;
}

// sorting-network comparator: descending value, ascending index on tie
#define CSW(a, b)                                                        \
    {                                                                    \
        bool sw = (v##a < v##b) || ((v##a == v##b) && (j##a > j##b));    \
        float tf = sw ? v##b : v##a;                                     \
        float uf = sw ? v##a : v##b;                                     \
        int ti = sw ? j##b : j##a;                                       \
        int ui = sw ? j##a : j##b;                                       \
        v##a = tf; v##b = uf; j##a = ti; j##b = ui;                      \
    }

// ---------------------------------------------------------------
// Kernel 3: per-token DPP (unchanged). 2 independent waves per
// 128-thread block, no __syncthreads.
// ---------------------------------------------------------------
__global__ __launch_bounds__(128) void dpp_kernel(
    const float* __restrict__ v, float* __restrict__ S,
    const float* __restrict__ KKT, const float* __restrict__ gate_p,
    float* __restrict__ y, float* __restrict__ denomArr)
{
    const int tid  = threadIdx.x;
    const int wid  = tid >> 6;
    const int lane = tid & 63;
    const int i = blockIdx.x * 2 + wid;
    const int n = blockIdx.y;
    const float* vh = v + (size_t)n * SEQ * HDIM;
    const float* KKTh = KKT + (size_t)n * 36 * 4096;
    float* Srow = S + ((size_t)n * SEQ + i) * SEQ;

    __shared__ float prow[2][SEQ];
    __shared__ float gramf[2][17][17];
    __shared__ int   eidx[2][17];
    __shared__ int   selS[2][SMAX];

    float sim8[8];
    #pragma unroll
    for (int m = 0; m < 8; ++m) {
        int j = lane + (m << 6);
        sim8[m] = (j <= i) ? Srow[j] : NEGINF;
    }
    if (lane < SMAX) selS[wid][lane] = i;

    {
        float v0 = sim8[0], v1 = sim8[1], v2 = sim8[2], v3 = sim8[3],
              v4 = sim8[4], v5 = sim8[5], v6 = sim8[6], v7 = sim8[7];
        int j0 = lane, j1 = lane + 64, j2 = lane + 128, j3 = lane + 192,
            j4 = lane + 256, j5 = lane + 320, j6 = lane + 384, j7 = lane + 448;
        CSW(0, 1) CSW(2, 3) CSW(4, 5) CSW(6, 7)
        CSW(0, 2) CSW(1, 3) CSW(4, 6) CSW(5, 7)
        CSW(1, 2) CSW(5, 6)
        CSW(0, 4) CSW(1, 5) CSW(2, 6) CSW(3, 7)
        CSW(2, 4) CSW(3, 5)
        CSW(1, 2) CSW(3, 4) CSW(5, 6)

        if (lane == 0) eidx[wid][0] = i;
        #pragma unroll
        for (int s = 0; s < TOPM; ++s) {
            float rv = v0;
            #pragma unroll
            for (int off = 32; off; off >>= 1)
                rv = fmaxf(rv, __shfl_xor(rv, off));
            unsigned long long tied = __ballot(v0 == rv);
            int ri;
            if (__popcll(tied) == 1) {
                ri = __shfl(j0, (int)__builtin_ctzll(tied));
            } else {
                int cnd = (v0 == rv) ? j0 : 0x7FFFFFFF;
                #pragma unroll
                for (int off = 32; off; off >>= 1)
                    cnd = min(cnd, __shfl_xor(cnd, off));
                ri = cnd;
            }
            if (lane == 0) eidx[wid][1 + s] = ri;
            if (v0 == rv && j0 == ri) {
                v0 = v1; j0 = j1; v1 = v2; j1 = j2; v2 = v3; j2 = j3;
                v3 = v4; j3 = j4; v4 = v5; j4 = j5; v5 = v6; j5 = j6;
                v6 = v7; j6 = j7; v7 = -3e38f; j7 = 1023;
            }
        }
    }

    const float scale = 0.125f;
    float lm = -3e38f;
    #pragma unroll
    for (int m = 0; m < 8; ++m) lm = fmaxf(lm, sim8[m]);
    #pragma unroll
    for (int off = 32; off; off >>= 1) lm = fmaxf(lm, __shfl_xor(lm, off));
    const float mx = lm * scale;
    float sum = 0.f;
    #pragma unroll
    for (int m = 0; m < 8; ++m) {
        float p = expf(sim8[m] * scale - mx);
        int j = lane + (m << 6);
        prow[wid][j] = p;
        Srow[j] = p;
        sum += p;
    }
    #pragma unroll
    for (int off = 32; off; off >>= 1) sum += __shfl_xor(sum, off);
    const float denom = sum;
    asm volatile("s_waitcnt lgkmcnt(0)" ::: "memory");

    for (int e = lane; e < 153; e += 64) {
        int a = (int)((sqrtf(8.f * (float)e + 1.f) - 1.f) * 0.5f);
        int st = (a * (a + 1)) >> 1;
        if (st > e) { --a; st = (a * (a + 1)) >> 1; }
        else if (st + a + 1 <= e) { ++a; st = (a * (a + 1)) >> 1; }
        int b = e - st;
        int ra = eidx[wid][a], rb = eidx[wid][b];
        int row = ra > rb ? ra : rb;
        int col = ra > rb ? rb : ra;
        int itt = row >> 6, jtt = col >> 6;
        int p = ((itt * (itt + 1)) >> 1) + jtt;
        float s = KKTh[((size_t)p * 64 + (row & 63)) * 64 + (col & 63)];
        gramf[wid][a][b] = s;
        gramf[wid][b][a] = s;
    }
    asm volatile("s_waitcnt lgkmcnt(0)" ::: "memory");

    int sc = 1;
    {
        const int c = lane;
        const bool isCand = (c < TOPM);
        const int nvalid = (i + 1 < TOPM) ? (i + 1) : TOPM;
        bool active = isCand && (c < nvalid) && (eidx[wid][1 + c] != i);
        double zc[7];
        #pragma unroll
        for (int t = 0; t < 7; ++t) zc[t] = 0.0;
        double det = (double)gramf[wid][0][0];
        double cur = 0.0;
        double invL00 = rsqrt64(det > 0.0 ? det : 1e-30);
        double dcv = 0.0;
        if (isCand) {
            zc[0] = (double)gramf[wid][1 + c][0] * invL00;
            dcv = (double)gramf[wid][1 + c][1 + c] - zc[0] * zc[0];
        }

        for (int it2 = 0; it2 < SMAX - 1; ++it2) {
            double argc = det * dcv + 1e-6;
            double key = active ? (argc > 0.0 ? argc : 1e300) : -1.0;
            int rc = c;
            #pragma unroll
            for (int off = 1; off <= 8; off <<= 1) {
                double ov = __shfl_xor(key, off);
                int    oc = __shfl_xor(rc, off);
                if (ov > key || (ov == key && oc < rc)) { key = ov; rc = oc; }
            }
            rc = __shfl(rc, 0);
            bool any = (__any(active ? 1 : 0) != 0);
            double dbest = __shfl(dcv, rc);
            bool take;
            if (it2 < 2) {
                take = any;
            } else {
                double argb = det * dbest + 1e-6;
                bool pos = argb > 0.0;
                double score = hybrid_log(pos ? argb : 1.0) / (double)(sc + 1);
                take = any && (it2 < 3 || (pos && score > cur));
                if (take) cur = pos ? score : __builtin_nan("");
            }
            if (!take) break;

            double invLss = rsqrt64(dbest > 1e-30 ? dbest : 1e-30);
            double zb[7];
            #pragma unroll
            for (int t = 0; t < 7; ++t) zb[t] = __shfl(zc[t], rc);
            if (isCand) {
                double crossn = (double)gramf[wid][1 + c][1 + rc];
                double s2 = 0.0;
                #pragma unroll
                for (int t = 0; t < 7; ++t) s2 += zc[t] * zb[t];
                double znew = (crossn - s2) * invLss;
                #pragma unroll
                for (int t = 0; t < 7; ++t) if (t == sc) zc[t] = znew;
                dcv -= znew * znew;
            }
            det = det * dbest;
            if (c == rc) active = false;
            if (lane == 0) selS[wid][sc] = eidx[wid][1 + rc];
            ++sc;
        }
    }

    int selI[SMAX];
    #pragma unroll
    for (int s = 0; s < SMAX; ++s) selI[s] = selS[wid][s];
    float wsum = 0.f;
    #pragma unroll
    for (int s = 0; s < SMAX; ++s) if (s < sc) wsum += prow[wid][selI[s]];
    float yd = 0.f;
    #pragma unroll
    for (int s = 0; s < SMAX; ++s)
        if (s < sc) yd = fmaf(prow[wid][selI[s]], vh[selI[s] * HDIM + lane], yd);
    const float gp = gate_p[0];
    const float gate = 1.f / (1.f + expf(-gp));
    y[((size_t)n * SEQ + i) * HDIM + lane] = gate * yd / wsum;
    if (lane == 0) denomArr[n * SEQ + i] = denom;
}

// ---------------------------------------------------------------
// Kernel 4: y += (1-gate) * (P @ V)/denom (unchanged).
// ---------------------------------------------------------------
__global__ __launch_bounds__(256) void pv_gemm_kernel(
    const float* __restrict__ P, const float* __restrict__ v,
    const float* __restrict__ denomArr, const float* __restrict__ gate_p,
    float* __restrict__ y)
{
    __shared__ float Ps[32][36];
    __shared__ float Vs[32][68];
    const int tt = blockIdx.x;
    const int n  = blockIdx.y;
    const int t0 = tt * 32;
    const int tid = threadIdx.x;
    const float* Ph = P + (size_t)n * SEQ * SEQ;
    const float* vh = v + (size_t)n * SEQ * HDIM;
    const int tm = (tid >> 4) << 1;
    const int tn = (tid & 15) << 2;
    float acc[2][4] = {};
    const int jmax = t0 + 32;
    for (int j0 = 0; j0 < jmax; j0 += 32) {
        {
            int tok = tid >> 3, j4 = (tid & 7) << 2;
            *(float4*)&Ps[tok][j4] =
                *(const float4*)(Ph + (t0 + tok) * SEQ + j0 + j4);
        }
        #pragma unroll
        for (int l = 0; l < 2; ++l) {
            int idx = tid + l * 256;
            int j = idx >> 4, d4 = (idx & 15) << 2;
            *(float4*)&Vs[j][d4] = *(const float4*)(vh + (j0 + j) * HDIM + d4);
        }
        __syncthreads();
        #pragma unroll
        for (int j4 = 0; j4 < 8; ++j4) {
            float4 p0r = *(const float4*)&Ps[tm + 0][j4 << 2];
            float4 p1r = *(const float4*)&Ps[tm + 1][j4 << 2];
            float pr[2][4] = {{p0r.x, p0r.y, p0r.z, p0r.w},
                              {p1r.x, p1r.y, p1r.z, p1r.w}};
            #pragma unroll
            for (int l = 0; l < 4; ++l) {
                float4 v4 = *(const float4*)&Vs[(j4 << 2) + l][tn];
                float vv[4] = {v4.x, v4.y, v4.z, v4.w};
                #pragma unroll
                for (int u = 0; u < 2; ++u)
                    #pragma unroll
                    for (int w2 = 0; w2 < 4; ++w2)
                        acc[u][w2] = fmaf(pr[u][l], vv[w2], acc[u][w2]);
            }
        }
        __syncthreads();
    }
    const float gp = gate_p[0];
    const float gate = 1.f / (1.f + expf(-gp));
    #pragma unroll
    for (int u = 0; u < 2; ++u) {
        int i = t0 + tm + u;
        float den = denomArr[n * SEQ + i];
        #pragma unroll
        for (int w2 = 0; w2 < 4; ++w2) {
            int d = tn + w2;
            size_t off = ((size_t)n * SEQ + i) * HDIM + d;
            y[off] += (1.f - gate) * acc[u][w2] / den;
        }
    }
}

// ---------------------------------------------------------------
// Kernel 5a: proj partial GEMM, K-split x8, 128x64 tile, 8x4 micro
// (gathered A) — R13/R15 config.
// ---------------------------------------------------------------
__global__ __launch_bounds__(256) void proj_gemm_kernel(
    const float* __restrict__ y, const float* __restrict__ w,
    float* __restrict__ partial)
{
    __shared__ float As[128][36];
    __shared__ float Bs[32][68];
    const int bm = blockIdx.y * 128;
    const int bn = blockIdx.x * 64;
    const int kbase = blockIdx.z * 96;
    const int tid = threadIdx.x;
    const int tm = (tid >> 4) << 3;
    const int tn = (tid & 15) << 2;
    const int blk = tid >> 3;
    const int bln = (tid & 7) << 3;

    float acc[8][4] = {};
    for (int t = 0; t < 3; ++t) {
        const int k0 = kbase + t * 32;
        float4 av[4];
        #pragma unroll
        for (int l = 0; l < 4; ++l) {
            int idx = tid + l * 256;
            int row = bm + (idx >> 3);
            int col = k0 + ((idx & 7) << 2);
            int b_ = row >> 9, tk = row & 511;
            int h = col >> 6, d = col & 63;
            av[l] = *(const float4*)(y + ((((size_t)b_ * NHEAD + h) * SEQ) + tk) * HDIM + d);
        }
        float4 b0 = *(const float4*)(w + (k0 + blk) * CDIM + bn + bln);
        float4 b1 = *(const float4*)(w + (k0 + blk) * CDIM + bn + bln + 4);
        #pragma unroll
        for (int l = 0; l < 4; ++l) {
            int idx = tid + l * 256;
            int row = idx >> 3, kq = (idx & 7) << 2;
            *(float4*)&As[row][kq] = av[l];
        }
        *(float4*)&Bs[blk][bln] = b0;
        *(float4*)&Bs[blk][bln + 4] = b1;
        __syncthreads();
        #pragma unroll
        for (int k4 = 0; k4 < 8; ++k4) {
            float ar[8][4];
            #pragma unroll
            for (int u = 0; u < 8; ++u) {
                float4 a4 = *(const float4*)&As[tm + u][k4 << 2];
                ar[u][0] = a4.x; ar[u][1] = a4.y;
                ar[u][2] = a4.z; ar[u][3] = a4.w;
            }
            #pragma unroll
            for (int j = 0; j < 4; ++j) {
                float4 b4 = *(const float4*)&Bs[(k4 << 2) + j][tn];
                float bb[4] = {b4.x, b4.y, b4.z, b4.w};
                #pragma unroll
                for (int u = 0; u < 8; ++u)
                    #pragma unroll
                    for (int w2 = 0; w2 < 4; ++w2)
                        acc[u][w2] = fmaf(ar[u][j], bb[w2], acc[u][w2]);
            }
        }
        __syncthreads();
    }
    float* dst = partial + (size_t)blockIdx.z * (1024 * 768);
    #pragma unroll
    for (int u = 0; u < 8; ++u) {
        float4 o = {acc[u][0], acc[u][1], acc[u][2], acc[u][3]};
        *(float4*)(dst + (size_t)(bm + tm + u) * 768 + bn + tn) = o;
    }
}

// ---------------------------------------------------------------
// Kernel 5b: proj reduce: sum 8 partials (fixed order) + bias.
// ---------------------------------------------------------------
__global__ __launch_bounds__(256) void proj_reduce_kernel(
    const float* __restrict__ partial, const float* __restrict__ bias,
    float* __restrict__ out)
{
    const int idx = blockIdx.x * 256 + threadIdx.x;
    const int m = idx / 192;
    const int cc = (idx - m * 192) << 2;
    const size_t MN = (size_t)1024 * 768;
    float4 s = *(const float4*)(partial + (size_t)m * 768 + cc);
    #pragma unroll
    for (int z = 1; z < 8; ++z) {
        float4 p = *(const float4*)(partial + (size_t)z * MN + (size_t)m * 768 + cc);
        s.x += p.x; s.y += p.y; s.z += p.z; s.w += p.w;
    }
    float4 b4 = *(const float4*)(bias + cc);
    float4 o = {s.x + b4.x, s.y + b4.y, s.z + b4.z, s.w + b4.w};
    *(float4*)(out + (size_t)m * 768 + cc) = o;
}

extern "C" void kernel_launch(void* const* d_in, const int* in_sizes, int n_in,
                              void* d_out, int out_size, void* d_ws, size_t ws_size,
                              hipStream_t stream)
{
    const float* x      = (const float*)d_in[0];
    const float* w_qkv  = (const float*)d_in[1];
    const float* b_qkv  = (const float*)d_in[2];
    const float* w_proj = (const float*)d_in[3];
    const float* b_proj = (const float*)d_in[4];
    const float* gate_p = (const float*)d_in[5];
    float* out = (float*)d_out;

    float* ws = (float*)d_ws;
    const size_t HS = (size_t)NBATCH * NHEAD * SEQ * HDIM;   // 786432
    const size_t SS = (size_t)NBATCH * NHEAD * SEQ * SEQ;    // 6291456
    float* q   = ws;
    float* k   = q + HS;
    float* v   = k + HS;
    float* y   = v + HS;
    float* S   = y + HS;                 // sim->P in place; also scratch
    float* den = S + SS;
    float* KKT = den + 16384;            // 24*36*4096 floats, packed tiles

    // bf16x3 components live in the S region (free until qkkt):
    // x comps: 3 x 786432 ushort; wT comps: 3 x 1769472 ushort.
    unsigned short* us = (unsigned short*)S;
    unsigned short* xh = us;
    unsigned short* xm = us + 786432;
    unsigned short* xl = us + 1572864;
    unsigned short* wh = us + 2359296;
    unsigned short* wm = us + 2359296 + 1769472;
    unsigned short* wl = us + 2359296 + 3538944;   // total 7.67M ush < 12.6M

    split_x_kernel<<<768, 256, 0, stream>>>(x, xh, xm, xl);
    tsplit_w_kernel<<<dim3(36, 12), 256, 0, stream>>>(w_qkv, wh, wm, wl);
    qkv_mfma_kernel<<<dim3(36, 16), 256, 0, stream>>>(
        xh, xm, xl, wh, wm, wl, b_qkv, q, k, v);
    qkkt_kernel<<<dim3(36, NBATCH * NHEAD), 256, 0, stream>>>(q, k, S, KKT);
    dpp_kernel<<<dim3(SEQ / 2, NBATCH * NHEAD), 128, 0, stream>>>(
        v, S, KKT, gate_p, y, den);
    pv_gemm_kernel<<<dim3(SEQ / 32, NBATCH * NHEAD), 256, 0, stream>>>(
        S, v, den, gate_p, y);
    // proj partials (8*1024*768 floats) fill S (free after pv).
    proj_gemm_kernel<<<dim3(CDIM / 64, (NBATCH * SEQ) / 128, 8), 256, 0, stream>>>(
        y, w_proj, S);
    proj_reduce_kernel<<<768, 256, 0, stream>>>(S, b_proj, out);
}

// Round 19
// 163.614 us; speedup vs baseline: 1.3193x; 1.0380x over previous
//
#include <hip/hip_runtime.h>
#include <math.h>

// Problem constants
constexpr int SEQ   = 512;
constexpr int HDIM  = 64;
constexpr int NHEAD = 12;
constexpr int NBATCH = 2;
constexpr int CDIM  = 768;
constexpr int TOPM  = 16;
constexpr int SMAX  = 8;
constexpr float NEGINF = -1e30f;

typedef short bf16x8 __attribute__((ext_vector_type(8)));
typedef float f32x4  __attribute__((ext_vector_type(4)));

// async global->LDS, 16B per lane, wave-uniform LDS base
__device__ inline void gload_lds16(const void* src, void* lds_base)
{
    __builtin_amdgcn_global_load_lds(
        (const __attribute__((address_space(1))) void*)src,
        (__attribute__((address_space(3))) void*)lds_base, 16, 0, 0);
}

// RNE float->bf16 and back (finite data only)
__device__ inline unsigned short f2bf(float f)
{
    unsigned u = __float_as_uint(f);
    return (unsigned short)((u + 0x7FFFu + ((u >> 16) & 1u)) >> 16);
}
__device__ inline float bf2f(unsigned short h)
{
    return __uint_as_float((unsigned)h << 16);
}
__device__ inline void split3(float f, unsigned short& h,
                              unsigned short& m, unsigned short& l)
{
    h = f2bf(f);
    float r1 = f - bf2f(h);
    m = f2bf(r1);
    l = f2bf(r1 - bf2f(m));
}

// ---------------------------------------------------------------
// Prep 1: split x [1024][768] into 3 bf16 components (hi/mid/lo).
// ---------------------------------------------------------------
__global__ __launch_bounds__(256) void split_x_kernel(
    const float* __restrict__ x, unsigned short* __restrict__ xh,
    unsigned short* __restrict__ xm, unsigned short* __restrict__ xl)
{
    const int idx = (blockIdx.x * 256 + threadIdx.x) * 4;
    float4 v = *(const float4*)(x + idx);
    float vv[4] = {v.x, v.y, v.z, v.w};
    unsigned short h[4], m[4], l[4];
    #pragma unroll
    for (int e = 0; e < 4; ++e) split3(vv[e], h[e], m[e], l[e]);
    *(ushort4*)(xh + idx) = make_ushort4(h[0], h[1], h[2], h[3]);
    *(ushort4*)(xm + idx) = make_ushort4(m[0], m[1], m[2], m[3]);
    *(ushort4*)(xl + idx) = make_ushort4(l[0], l[1], l[2], l[3]);
}

// ---------------------------------------------------------------
// Prep 2: transpose w_qkv [768][2304] -> [2304][768] and split to
// 3 bf16 components. 64x64 LDS tile transpose.
// ---------------------------------------------------------------
__global__ __launch_bounds__(256) void tsplit_w_kernel(
    const float* __restrict__ w, unsigned short* __restrict__ wh,
    unsigned short* __restrict__ wm, unsigned short* __restrict__ wl)
{
    __shared__ float T[64][65];
    const int c0 = blockIdx.x * 64;   // col tile (36)
    const int k0 = blockIdx.y * 64;   // k tile (12)
    const int tid = threadIdx.x;
    #pragma unroll
    for (int i = 0; i < 16; ++i) {
        int idx = tid + i * 256;
        int kk = idx >> 6, cc = idx & 63;
        T[kk][cc] = w[(size_t)(k0 + kk) * (3 * CDIM) + c0 + cc];
    }
    __syncthreads();
    #pragma unroll
    for (int i = 0; i < 16; ++i) {
        int idx = tid + i * 256;
        int col = idx >> 6, kk = idx & 63;
        unsigned short h, m, l;
        split3(T[kk][col], h, m, l);
        size_t o = (size_t)(c0 + col) * CDIM + k0 + kk;
        wh[o] = h; wm[o] = m; wl[o] = l;
    }
}

// ---------------------------------------------------------------
// Kernel 1: QKV GEMM via bf16x3 MFMA. 64x64 tile, FOUR waves,
// K=768, bias fused. (R17 kernel, byte-identical.)
// ---------------------------------------------------------------
__global__ __launch_bounds__(256) void qkv_mfma_kernel(
    const unsigned short* __restrict__ xh, const unsigned short* __restrict__ xm,
    const unsigned short* __restrict__ xl, const unsigned short* __restrict__ wh,
    const unsigned short* __restrict__ wm, const unsigned short* __restrict__ wl,
    const float* __restrict__ bias,
    float* __restrict__ q, float* __restrict__ k, float* __restrict__ v)
{
    __shared__ unsigned short As[3][64 * 32];
    __shared__ unsigned short Bs[3][64 * 32];
    const int bn = blockIdx.x * 64;
    const int bm = blockIdx.y * 64;
    const int tid = threadIdx.x;
    const int wid = tid >> 6;
    const int lane = tid & 63;
    const int lrow = lane & 15;
    const int lk8 = (lane >> 4) << 3;

    f32x4 acc[4];
    #pragma unroll
    for (int b = 0; b < 4; ++b) acc[b] = (f32x4){0.f, 0.f, 0.f, 0.f};

    const unsigned short* xs[3] = {xh, xm, xl};
    const unsigned short* wsrc[3] = {wh, wm, wl};

    const int slot = wid * 64 + lane;
    const int srow = slot >> 2;
    const int sk8 = (slot & 3) << 3;

    for (int k0 = 0; k0 < CDIM; k0 += 32) {
        #pragma unroll
        for (int c = 0; c < 3; ++c)
            gload_lds16(xs[c] + (size_t)(bm + srow) * CDIM + k0 + sk8,
                        &As[c][wid * 512]);
        #pragma unroll
        for (int c = 0; c < 3; ++c)
            gload_lds16(wsrc[c] + (size_t)(bn + srow) * CDIM + k0 + sk8,
                        &Bs[c][wid * 512]);
        __syncthreads();

        bf16x8 bf[3][4];
        #pragma unroll
        for (int c = 0; c < 3; ++c)
            #pragma unroll
            for (int ni = 0; ni < 4; ++ni)
                bf[c][ni] = *(const bf16x8*)&Bs[c][(ni * 16 + lrow) * 32 + lk8];

        bf16x8 ah = *(const bf16x8*)&As[0][(wid * 16 + lrow) * 32 + lk8];
        bf16x8 am = *(const bf16x8*)&As[1][(wid * 16 + lrow) * 32 + lk8];
        bf16x8 al = *(const bf16x8*)&As[2][(wid * 16 + lrow) * 32 + lk8];
        #pragma unroll
        for (int ni = 0; ni < 4; ++ni) {
            f32x4 a = acc[ni];
            a = __builtin_amdgcn_mfma_f32_16x16x32_bf16(al, bf[0][ni], a, 0, 0, 0);
            a = __builtin_amdgcn_mfma_f32_16x16x32_bf16(ah, bf[2][ni], a, 0, 0, 0);
            a = __builtin_amdgcn_mfma_f32_16x16x32_bf16(am, bf[1][ni], a, 0, 0, 0);
            a = __builtin_amdgcn_mfma_f32_16x16x32_bf16(am, bf[0][ni], a, 0, 0, 0);
            a = __builtin_amdgcn_mfma_f32_16x16x32_bf16(ah, bf[1][ni], a, 0, 0, 0);
            a = __builtin_amdgcn_mfma_f32_16x16x32_bf16(ah, bf[0][ni], a, 0, 0, 0);
            acc[ni] = a;
        }
        __syncthreads();
    }

    const int rbase = (lane >> 4) << 2;
    #pragma unroll
    for (int ni = 0; ni < 4; ++ni) {
        int cc = bn + ni * 16 + lrow;
        float bval = bias[cc];
        int part = cc / CDIM;
        int c2 = cc - part * CDIM;
        int hh = c2 >> 6, d = c2 & 63;
        float* dst = (part == 0) ? q : ((part == 1) ? k : v);
        #pragma unroll
        for (int r = 0; r < 4; ++r) {
            int m = bm + wid * 16 + rbase + r;
            int b_ = m >> 9, t = m & 511;
            dst[((((size_t)b_ * NHEAD + hh) * SEQ) + t) * HDIM + d] =
                acc[ni][r] + bval;
        }
    }
}

// ---------------------------------------------------------------
// Kernel 2: fused S = QK^T and KKT via bf16x3 MFMA, 4 waves.
// fp32 Q/Ka/Kb tiles staged via global_load_lds (24KB), split3 to
// bf16x3 ON-THE-FLY in registers (arithmetic identical to R16's
// validated comps path; no extra ws storage). 64x64 lower-tri
// tiles per head, K=64 (2 ksteps).
// ---------------------------------------------------------------
__global__ __launch_bounds__(256) void qkkt_mfma_kernel(
    const float* __restrict__ q, const float* __restrict__ k,
    float* __restrict__ S, float* __restrict__ KKT)
{
    __shared__ float Qs[64 * 32];
    __shared__ float Kas[64 * 32];
    __shared__ float Kbs[64 * 32];
    const int e = blockIdx.x;
    const int n = blockIdx.y;
    int it = 0, start = 0;
    while (start + it + 1 <= e) { start += it + 1; ++it; }
    const int jt = e - start;
    const int tid = threadIdx.x;
    const int wid = tid >> 6;
    const int lane = tid & 63;
    const int lrow = lane & 15;
    const int lk8 = (lane >> 4) << 3;
    const float* qh = q + (size_t)n * SEQ * HDIM;
    const float* kh = k + (size_t)n * SEQ * HDIM;

    f32x4 accS[4], accG[4];
    #pragma unroll
    for (int b = 0; b < 4; ++b) {
        accS[b] = (f32x4){0.f, 0.f, 0.f, 0.f};
        accG[b] = (f32x4){0.f, 0.f, 0.f, 0.f};
    }

    #pragma unroll
    for (int ks = 0; ks < 2; ++ks) {
        const int k0 = ks * 32;
        // stage 3 fp32 tiles: 64 rows x 32 floats = 512 granules each,
        // 256 threads -> 2 issues per buffer
        #pragma unroll
        for (int l = 0; l < 2; ++l) {
            int g = l * 256 + wid * 64 + lane;   // granule id
            int r = g >> 3, f4 = (g & 7) << 2;
            float* dstQ = Qs + (l * 256 + wid * 64) * 4;
            float* dstA = Kas + (l * 256 + wid * 64) * 4;
            float* dstB = Kbs + (l * 256 + wid * 64) * 4;
            gload_lds16(qh + (size_t)(it * 64 + r) * HDIM + k0 + f4, dstQ);
            gload_lds16(kh + (size_t)(it * 64 + r) * HDIM + k0 + f4, dstA);
            gload_lds16(kh + (size_t)(jt * 64 + r) * HDIM + k0 + f4, dstB);
        }
        __syncthreads();   // drains vmcnt before LDS reads

        // A fragments (Q and Ka) for this wave's 16-row strip
        bf16x8 qfh, qfm, qfl, afh, afm, afl;
        {
            const float* qr = Qs + (wid * 16 + lrow) * 32 + lk8;
            const float* ar = Kas + (wid * 16 + lrow) * 32 + lk8;
            #pragma unroll
            for (int e2 = 0; e2 < 8; ++e2) {
                unsigned short h, m, l;
                split3(qr[e2], h, m, l);
                qfh[e2] = (short)h; qfm[e2] = (short)m; qfl[e2] = (short)l;
                split3(ar[e2], h, m, l);
                afh[e2] = (short)h; afm[e2] = (short)m; afl[e2] = (short)l;
            }
        }
        // B fragments (Kb), 4 col-frags
        bf16x8 bfh[4], bfm[4], bfl[4];
        #pragma unroll
        for (int ni = 0; ni < 4; ++ni) {
            const float* br = Kbs + (ni * 16 + lrow) * 32 + lk8;
            #pragma unroll
            for (int e2 = 0; e2 < 8; ++e2) {
                unsigned short h, m, l;
                split3(br[e2], h, m, l);
                bfh[ni][e2] = (short)h; bfm[ni][e2] = (short)m; bfl[ni][e2] = (short)l;
            }
        }
        #pragma unroll
        for (int ni = 0; ni < 4; ++ni) {
            f32x4 a = accS[ni];
            a = __builtin_amdgcn_mfma_f32_16x16x32_bf16(qfl, bfh[ni], a, 0, 0, 0);
            a = __builtin_amdgcn_mfma_f32_16x16x32_bf16(qfh, bfl[ni], a, 0, 0, 0);
            a = __builtin_amdgcn_mfma_f32_16x16x32_bf16(qfm, bfm[ni], a, 0, 0, 0);
            a = __builtin_amdgcn_mfma_f32_16x16x32_bf16(qfm, bfh[ni], a, 0, 0, 0);
            a = __builtin_amdgcn_mfma_f32_16x16x32_bf16(qfh, bfm[ni], a, 0, 0, 0);
            a = __builtin_amdgcn_mfma_f32_16x16x32_bf16(qfh, bfh[ni], a, 0, 0, 0);
            accS[ni] = a;
            f32x4 g = accG[ni];
            g = __builtin_amdgcn_mfma_f32_16x16x32_bf16(afl, bfh[ni], g, 0, 0, 0);
            g = __builtin_amdgcn_mfma_f32_16x16x32_bf16(afh, bfl[ni], g, 0, 0, 0);
            g = __builtin_amdgcn_mfma_f32_16x16x32_bf16(afm, bfm[ni], g, 0, 0, 0);
            g = __builtin_amdgcn_mfma_f32_16x16x32_bf16(afm, bfh[ni], g, 0, 0, 0);
            g = __builtin_amdgcn_mfma_f32_16x16x32_bf16(afh, bfm[ni], g, 0, 0, 0);
            g = __builtin_amdgcn_mfma_f32_16x16x32_bf16(afh, bfh[ni], g, 0, 0, 0);
            accG[ni] = g;
        }
        __syncthreads();
    }

    const int rbase = (lane >> 4) << 2;
    float* gdst = KKT + ((size_t)n * 36 + e) * 4096;
    #pragma unroll
    for (int ni = 0; ni < 4; ++ni) {
        int coll = ni * 16 + lrow;
        int col = jt * 64 + coll;
        #pragma unroll
        for (int r = 0; r < 4; ++r) {
            int rowl = wid * 16 + rbase + r;
            int row = it * 64 + rowl;
            S[((size_t)n * SEQ + row) * SEQ + col] = accS[ni][r];
            gdst[rowl * 64 + coll] = accG[ni][r];
        }
    }
}

// hybrid log: exact exponent + hardware f32 log2 of mantissa.
__device__ inline double hybrid_log(double a)
{
    unsigned long long b = __double_as_longlong(a);
    int e2 = (int)((b >> 52) & 0x7FF) - 1022;
    double m = __longlong_as_double((b & 0x000FFFFFFFFFFFFFULL) |
                                    0x3FE0000000000000ULL);   // [0.5,1)
    return ((double)__log2f((float)m) + (double)e2) * 0.6931471805599453;
}

// 1/sqrt(x) via f32 rsqrt + one f64 Newton step (rel err ~1.5e-14).
__device__ inline double rsqrt64(double x)
{
    double r = (double)rsqrtf((float)x);
    r = r * (1.5 - 0.5 * x * r * r);
    return r;
}

// sorting-network comparator: descending value, ascending index on tie
#define CSW(a, b)                                                        \
    {                                                                    \
        bool sw = (v##a < v##b) || ((v##a == v##b) && (j##a > j##b));    \
        float tf = sw ? v##b : v##a;                                     \
        float uf = sw ? v##a : v##b;                                     \
        int ti = sw ? j##b : j##a;                                       \
        int ui = sw ? j##a : j##b;                                       \
        v##a = tf; v##b = uf; j##a = ti; j##b = ui;                      \
    }

// ---------------------------------------------------------------
// Kernel 3: per-token DPP (unchanged). 2 independent waves per
// 128-thread block, no __syncthreads.
// ---------------------------------------------------------------
__global__ __launch_bounds__(128) void dpp_kernel(
    const float* __restrict__ v, float* __restrict__ S,
    const float* __restrict__ KKT, const float* __restrict__ gate_p,
    float* __restrict__ y, float* __restrict__ denomArr)
{
    const int tid  = threadIdx.x;
    const int wid  = tid >> 6;
    const int lane = tid & 63;
    const int i = blockIdx.x * 2 + wid;
    const int n = blockIdx.y;
    const float* vh = v + (size_t)n * SEQ * HDIM;
    const float* KKTh = KKT + (size_t)n * 36 * 4096;
    float* Srow = S + ((size_t)n * SEQ + i) * SEQ;

    __shared__ float prow[2][SEQ];
    __shared__ float gramf[2][17][17];
    __shared__ int   eidx[2][17];
    __shared__ int   selS[2][SMAX];

    float sim8[8];
    #pragma unroll
    for (int m = 0; m < 8; ++m) {
        int j = lane + (m << 6);
        sim8[m] = (j <= i) ? Srow[j] : NEGINF;
    }
    if (lane < SMAX) selS[wid][lane] = i;

    {
        float v0 = sim8[0], v1 = sim8[1], v2 = sim8[2], v3 = sim8[3],
              v4 = sim8[4], v5 = sim8[5], v6 = sim8[6], v7 = sim8[7];
        int j0 = lane, j1 = lane + 64, j2 = lane + 128, j3 = lane + 192,
            j4 = lane + 256, j5 = lane + 320, j6 = lane + 384, j7 = lane + 448;
        CSW(0, 1) CSW(2, 3) CSW(4, 5) CSW(6, 7)
        CSW(0, 2) CSW(1, 3) CSW(4, 6) CSW(5, 7)
        CSW(1, 2) CSW(5, 6)
        CSW(0, 4) CSW(1, 5) CSW(2, 6) CSW(3, 7)
        CSW(2, 4) CSW(3, 5)
        CSW(1, 2) CSW(3, 4) CSW(5, 6)

        if (lane == 0) eidx[wid][0] = i;
        #pragma unroll
        for (int s = 0; s < TOPM; ++s) {
            float rv = v0;
            #pragma unroll
            for (int off = 32; off; off >>= 1)
                rv = fmaxf(rv, __shfl_xor(rv, off));
            unsigned long long tied = __ballot(v0 == rv);
            int ri;
            if (__popcll(tied) == 1) {
                ri = __shfl(j0, (int)__builtin_ctzll(tied));
            } else {
                int cnd = (v0 == rv) ? j0 : 0x7FFFFFFF;
                #pragma unroll
                for (int off = 32; off; off >>= 1)
                    cnd = min(cnd, __shfl_xor(cnd, off));
                ri = cnd;
            }
            if (lane == 0) eidx[wid][1 + s] = ri;
            if (v0 == rv && j0 == ri) {
                v0 = v1; j0 = j1; v1 = v2; j1 = j2; v2 = v3; j2 = j3;
                v3 = v4; j3 = j4; v4 = v5; j4 = j5; v5 = v6; j5 = j6;
                v6 = v7; j6 = j7; v7 = -3e38f; j7 = 1023;
            }
        }
    }

    const float scale = 0.125f;
    float lm = -3e38f;
    #pragma unroll
    for (int m = 0; m < 8; ++m) lm = fmaxf(lm, sim8[m]);
    #pragma unroll
    for (int off = 32; off; off >>= 1) lm = fmaxf(lm, __shfl_xor(lm, off));
    const float mx = lm * scale;
    float sum = 0.f;
    #pragma unroll
    for (int m = 0; m < 8; ++m) {
        float p = expf(sim8[m] * scale - mx);
        int j = lane + (m << 6);
        prow[wid][j] = p;
        Srow[j] = p;
        sum += p;
    }
    #pragma unroll
    for (int off = 32; off; off >>= 1) sum += __shfl_xor(sum, off);
    const float denom = sum;
    asm volatile("s_waitcnt lgkmcnt(0)" ::: "memory");

    for (int e = lane; e < 153; e += 64) {
        int a = (int)((sqrtf(8.f * (float)e + 1.f) - 1.f) * 0.5f);
        int st = (a * (a + 1)) >> 1;
        if (st > e) { --a; st = (a * (a + 1)) >> 1; }
        else if (st + a + 1 <= e) { ++a; st = (a * (a + 1)) >> 1; }
        int b = e - st;
        int ra = eidx[wid][a], rb = eidx[wid][b];
        int row = ra > rb ? ra : rb;
        int col = ra > rb ? rb : ra;
        int itt = row >> 6, jtt = col >> 6;
        int p = ((itt * (itt + 1)) >> 1) + jtt;
        float s = KKTh[((size_t)p * 64 + (row & 63)) * 64 + (col & 63)];
        gramf[wid][a][b] = s;
        gramf[wid][b][a] = s;
    }
    asm volatile("s_waitcnt lgkmcnt(0)" ::: "memory");

    int sc = 1;
    {
        const int c = lane;
        const bool isCand = (c < TOPM);
        const int nvalid = (i + 1 < TOPM) ? (i + 1) : TOPM;
        bool active = isCand && (c < nvalid) && (eidx[wid][1 + c] != i);
        double zc[7];
        #pragma unroll
        for (int t = 0; t < 7; ++t) zc[t] = 0.0;
        double det = (double)gramf[wid][0][0];
        double cur = 0.0;
        double invL00 = rsqrt64(det > 0.0 ? det : 1e-30);
        double dcv = 0.0;
        if (isCand) {
            zc[0] = (double)gramf[wid][1 + c][0] * invL00;
            dcv = (double)gramf[wid][1 + c][1 + c] - zc[0] * zc[0];
        }

        for (int it2 = 0; it2 < SMAX - 1; ++it2) {
            double argc = det * dcv + 1e-6;
            double key = active ? (argc > 0.0 ? argc : 1e300) : -1.0;
            int rc = c;
            #pragma unroll
            for (int off = 1; off <= 8; off <<= 1) {
                double ov = __shfl_xor(key, off);
                int    oc = __shfl_xor(rc, off);
                if (ov > key || (ov == key && oc < rc)) { key = ov; rc = oc; }
            }
            rc = __shfl(rc, 0);
            bool any = (__any(active ? 1 : 0) != 0);
            double dbest = __shfl(dcv, rc);
            bool take;
            if (it2 < 2) {
                take = any;
            } else {
                double argb = det * dbest + 1e-6;
                bool pos = argb > 0.0;
                double score = hybrid_log(pos ? argb : 1.0) / (double)(sc + 1);
                take = any && (it2 < 3 || (pos && score > cur));
                if (take) cur = pos ? score : __builtin_nan("");
            }
            if (!take) break;

            double invLss = rsqrt64(dbest > 1e-30 ? dbest : 1e-30);
            double zb[7];
            #pragma unroll
            for (int t = 0; t < 7; ++t) zb[t] = __shfl(zc[t], rc);
            if (isCand) {
                double crossn = (double)gramf[wid][1 + c][1 + rc];
                double s2 = 0.0;
                #pragma unroll
                for (int t = 0; t < 7; ++t) s2 += zc[t] * zb[t];
                double znew = (crossn - s2) * invLss;
                #pragma unroll
                for (int t = 0; t < 7; ++t) if (t == sc) zc[t] = znew;
                dcv -= znew * znew;
            }
            det = det * dbest;
            if (c == rc) active = false;
            if (lane == 0) selS[wid][sc] = eidx[wid][1 + rc];
            ++sc;
        }
    }

    int selI[SMAX];
    #pragma unroll
    for (int s = 0; s < SMAX; ++s) selI[s] = selS[wid][s];
    float wsum = 0.f;
    #pragma unroll
    for (int s = 0; s < SMAX; ++s) if (s < sc) wsum += prow[wid][selI[s]];
    float yd = 0.f;
    #pragma unroll
    for (int s = 0; s < SMAX; ++s)
        if (s < sc) yd = fmaf(prow[wid][selI[s]], vh[selI[s] * HDIM + lane], yd);
    const float gp = gate_p[0];
    const float gate = 1.f / (1.f + expf(-gp));
    y[((size_t)n * SEQ + i) * HDIM + lane] = gate * yd / wsum;
    if (lane == 0) denomArr[n * SEQ + i] = denom;
}

// ---------------------------------------------------------------
// Kernel 4: y += (1-gate) * (P @ V)/denom (unchanged).
// ---------------------------------------------------------------
__global__ __launch_bounds__(256) void pv_gemm_kernel(
    const float* __restrict__ P, const float* __restrict__ v,
    const float* __restrict__ denomArr, const float* __restrict__ gate_p,
    float* __restrict__ y)
{
    __shared__ float Ps[32][36];
    __shared__ float Vs[32][68];
    const int tt = blockIdx.x;
    const int n  = blockIdx.y;
    const int t0 = tt * 32;
    const int tid = threadIdx.x;
    const float* Ph = P + (size_t)n * SEQ * SEQ;
    const float* vh = v + (size_t)n * SEQ * HDIM;
    const int tm = (tid >> 4) << 1;
    const int tn = (tid & 15) << 2;
    float acc[2][4] = {};
    const int jmax = t0 + 32;
    for (int j0 = 0; j0 < jmax; j0 += 32) {
        {
            int tok = tid >> 3, j4 = (tid & 7) << 2;
            *(float4*)&Ps[tok][j4] =
                *(const float4*)(Ph + (t0 + tok) * SEQ + j0 + j4);
        }
        #pragma unroll
        for (int l = 0; l < 2; ++l) {
            int idx = tid + l * 256;
            int j = idx >> 4, d4 = (idx & 15) << 2;
            *(float4*)&Vs[j][d4] = *(const float4*)(vh + (j0 + j) * HDIM + d4);
        }
        __syncthreads();
        #pragma unroll
        for (int j4 = 0; j4 < 8; ++j4) {
            float4 p0r = *(const float4*)&Ps[tm + 0][j4 << 2];
            float4 p1r = *(const float4*)&Ps[tm + 1][j4 << 2];
            float pr[2][4] = {{p0r.x, p0r.y, p0r.z, p0r.w},
                              {p1r.x, p1r.y, p1r.z, p1r.w}};
            #pragma unroll
            for (int l = 0; l < 4; ++l) {
                float4 v4 = *(const float4*)&Vs[(j4 << 2) + l][tn];
                float vv[4] = {v4.x, v4.y, v4.z, v4.w};
                #pragma unroll
                for (int u = 0; u < 2; ++u)
                    #pragma unroll
                    for (int w2 = 0; w2 < 4; ++w2)
                        acc[u][w2] = fmaf(pr[u][l], vv[w2], acc[u][w2]);
            }
        }
        __syncthreads();
    }
    const float gp = gate_p[0];
    const float gate = 1.f / (1.f + expf(-gp));
    #pragma unroll
    for (int u = 0; u < 2; ++u) {
        int i = t0 + tm + u;
        float den = denomArr[n * SEQ + i];
        #pragma unroll
        for (int w2 = 0; w2 < 4; ++w2) {
            int d = tn + w2;
            size_t off = ((size_t)n * SEQ + i) * HDIM + d;
            y[off] += (1.f - gate) * acc[u][w2] / den;
        }
    }
}

// ---------------------------------------------------------------
// Kernel 5a: proj partial GEMM, K-split x8, 128x64 tile, 8x4 micro
// (gathered A) — unchanged.
// ---------------------------------------------------------------
__global__ __launch_bounds__(256) void proj_gemm_kernel(
    const float* __restrict__ y, const float* __restrict__ w,
    float* __restrict__ partial)
{
    __shared__ float As[128][36];
    __shared__ float Bs[32][68];
    const int bm = blockIdx.y * 128;
    const int bn = blockIdx.x * 64;
    const int kbase = blockIdx.z * 96;
    const int tid = threadIdx.x;
    const int tm = (tid >> 4) << 3;
    const int tn = (tid & 15) << 2;
    const int blk = tid >> 3;
    const int bln = (tid & 7) << 3;

    float acc[8][4] = {};
    for (int t = 0; t < 3; ++t) {
        const int k0 = kbase + t * 32;
        float4 av[4];
        #pragma unroll
        for (int l = 0; l < 4; ++l) {
            int idx = tid + l * 256;
            int row = bm + (idx >> 3);
            int col = k0 + ((idx & 7) << 2);
            int b_ = row >> 9, tk = row & 511;
            int h = col >> 6, d = col & 63;
            av[l] = *(const float4*)(y + ((((size_t)b_ * NHEAD + h) * SEQ) + tk) * HDIM + d);
        }
        float4 b0 = *(const float4*)(w + (k0 + blk) * CDIM + bn + bln);
        float4 b1 = *(const float4*)(w + (k0 + blk) * CDIM + bn + bln + 4);
        #pragma unroll
        for (int l = 0; l < 4; ++l) {
            int idx = tid + l * 256;
            int row = idx >> 3, kq = (idx & 7) << 2;
            *(float4*)&As[row][kq] = av[l];
        }
        *(float4*)&Bs[blk][bln] = b0;
        *(float4*)&Bs[blk][bln + 4] = b1;
        __syncthreads();
        #pragma unroll
        for (int k4 = 0; k4 < 8; ++k4) {
            float ar[8][4];
            #pragma unroll
            for (int u = 0; u < 8; ++u) {
                float4 a4 = *(const float4*)&As[tm + u][k4 << 2];
                ar[u][0] = a4.x; ar[u][1] = a4.y;
                ar[u][2] = a4.z; ar[u][3] = a4.w;
            }
            #pragma unroll
            for (int j = 0; j < 4; ++j) {
                float4 b4 = *(const float4*)&Bs[(k4 << 2) + j][tn];
                float bb[4] = {b4.x, b4.y, b4.z, b4.w};
                #pragma unroll
                for (int u = 0; u < 8; ++u)
                    #pragma unroll
                    for (int w2 = 0; w2 < 4; ++w2)
                        acc[u][w2] = fmaf(ar[u][j], bb[w2], acc[u][w2]);
            }
        }
        __syncthreads();
    }
    float* dst = partial + (size_t)blockIdx.z * (1024 * 768);
    #pragma unroll
    for (int u = 0; u < 8; ++u) {
        float4 o = {acc[u][0], acc[u][1], acc[u][2], acc[u][3]};
        *(float4*)(dst + (size_t)(bm + tm + u) * 768 + bn + tn) = o;
    }
}

// ---------------------------------------------------------------
// Kernel 5b: proj reduce: sum 8 partials (fixed order) + bias.
// ---------------------------------------------------------------
__global__ __launch_bounds__(256) void proj_reduce_kernel(
    const float* __restrict__ partial, const float* __restrict__ bias,
    float* __restrict__ out)
{
    const int idx = blockIdx.x * 256 + threadIdx.x;
    const int m = idx / 192;
    const int cc = (idx - m * 192) << 2;
    const size_t MN = (size_t)1024 * 768;
    float4 s = *(const float4*)(partial + (size_t)m * 768 + cc);
    #pragma unroll
    for (int z = 1; z < 8; ++z) {
        float4 p = *(const float4*)(partial + (size_t)z * MN + (size_t)m * 768 + cc);
        s.x += p.x; s.y += p.y; s.z += p.z; s.w += p.w;
    }
    float4 b4 = *(const float4*)(bias + cc);
    float4 o = {s.x + b4.x, s.y + b4.y, s.z + b4.z, s.w + b4.w};
    *(float4*)(out + (size_t)m * 768 + cc) = o;
}

extern "C" void kernel_launch(void* const* d_in, const int* in_sizes, int n_in,
                              void* d_out, int out_size, void* d_ws, size_t ws_size,
                              hipStream_t stream)
{
    const float* x      = (const float*)d_in[0];
    const float* w_qkv  = (const float*)d_in[1];
    const float* b_qkv  = (const float*)d_in[2];
    const float* w_proj = (const float*)d_in[3];
    const float* b_proj = (const float*)d_in[4];
    const float* gate_p = (const float*)d_in[5];
    float* out = (float*)d_out;

    float* ws = (float*)d_ws;
    const size_t HS = (size_t)NBATCH * NHEAD * SEQ * HDIM;   // 786432
    const size_t SS = (size_t)NBATCH * NHEAD * SEQ * SEQ;    // 6291456
    float* q   = ws;
    float* k   = q + HS;
    float* v   = k + HS;
    float* y   = v + HS;
    float* S   = y + HS;                 // sim->P in place; also scratch
    float* den = S + SS;
    float* KKT = den + 16384;            // 24*36*4096 floats, packed tiles

    // bf16x3 components live in the S region (free until qkkt):
    unsigned short* us = (unsigned short*)S;
    unsigned short* xh = us;
    unsigned short* xm = us + 786432;
    unsigned short* xl = us + 1572864;
    unsigned short* wh = us + 2359296;
    unsigned short* wm = us + 2359296 + 1769472;
    unsigned short* wl = us + 2359296 + 3538944;   // total 7.67M ush < 12.6M

    split_x_kernel<<<768, 256, 0, stream>>>(x, xh, xm, xl);
    tsplit_w_kernel<<<dim3(36, 12), 256, 0, stream>>>(w_qkv, wh, wm, wl);
    qkv_mfma_kernel<<<dim3(36, 16), 256, 0, stream>>>(
        xh, xm, xl, wh, wm, wl, b_qkv, q, k, v);
    qkkt_mfma_kernel<<<dim3(36, NBATCH * NHEAD), 256, 0, stream>>>(q, k, S, KKT);
    dpp_kernel<<<dim3(SEQ / 2, NBATCH * NHEAD), 128, 0, stream>>>(
        v, S, KKT, gate_p, y, den);
    pv_gemm_kernel<<<dim3(SEQ / 32, NBATCH * NHEAD), 256, 0, stream>>>(
        S, v, den, gate_p, y);
    // proj partials (8*1024*768 floats) fill S (free after pv).
    proj_gemm_kernel<<<dim3(CDIM / 64, (NBATCH * SEQ) / 128, 8), 256, 0, stream>>>(
        y, w_proj, S);
    proj_reduce_kernel<<<768, 256, 0, stream>>>(S, b_proj, out);
}